// Round 6
// baseline (105.638 us; speedup 1.0000x reference)
//
#include <hip/hip_runtime.h>
#include <math.h>

#define CIN 64
#define HH 32
#define WW 32
#define NO 64
#define NCK (CIN * 9)          // 576
#define NW  (NO * NCK)         // 36864
#define LUT_N 1024

// ws float layout: [0,NW): W_T[ck][o] = 512 - SZ16*theta[o][ck]   (coalesced in o)
//                  [NW, NW+NCK): tau_s[ck] = (min_o theta[o][ck] - 8/SZ) * SZ16
//                  [NW+NCK, +2048): LUT float2[1024] (t-domain PWL, as R5)
#define WS_TAU NW
#define WS_LUT (NW + NCK)      // 37440 floats -> byte offset 149760 (8B aligned)

constexpr float SZf  = 19.235933878519512f;          // log2(e)/phi
constexpr float SZ16 = 16.0f * 19.235933878519512f;
constexpr float MARG = 8.0f / 19.235933878519512f;   // z > -8 margin in x-units

__global__ __launch_bounds__(256) void prep_kernel(const float* __restrict__ theta,
                                                   float* __restrict__ ws) {
    const int b = blockIdx.x, t = threadIdx.x;
    if (b < NW / 256) {                      // 144 blocks: transposed weight xform
        int i = b * 256 + t;                 // i = ck*64 + o
        int o = i & 63, ck = i >> 6;
        ws[i] = fmaf(theta[o * NCK + ck], -SZ16, 512.0f);
    } else if (b < NW / 256 + 3) {           // 3 blocks: per-(c,k) skip threshold
        int ck = (b - NW / 256) * 256 + t;
        if (ck < NCK) {
            float mn = 1e30f;
            for (int o = 0; o < NO; ++o) mn = fminf(mn, theta[o * NCK + ck]);
            ws[WS_TAU + ck] = (mn - MARG) * SZ16;
        }
    } else {                                 // 1 block: LUT build (double)
        const double D2 = 9.6179661929342026;   // 0.5/(0.075*ln2)
        float2* lut = (float2*)(ws + WS_LUT);
        for (int j = t; j < LUT_N; j += 256) {
            double z0 = -32.0 + j * 0.0625, z1 = z0 + 0.0625;
            double f0 = log2(1.0 + exp2(z0)), f1 = log2(1.0 + exp2(z1));
            double r0 = log2(1.0 + exp2(z0 - D2)), r1 = log2(1.0 + exp2(z1 - D2));
            double g0 = f0 * f0 - r0 * r0, g1 = f1 * f1 - r1 * r1;
            double S = g1 - g0, B = g0 - S * (double)j;
            lut[j] = make_float2((float)S, (float)B);
        }
    }
}

// One wave per output pixel (n,ho,wo); lane = output channel o.
// Lanes 0..8 carry the 9 taps' x values for the skip test; active taps are
// processed in a wave-uniform ctz loop (all values scalar except W[o]/acc).
__global__ __launch_bounds__(256) void ekv_kernel(
        const float* __restrict__ x, const float* __restrict__ ws,
        float* __restrict__ out) {
    constexpr float OS = 0.020018875579925058f;  // ln2^2 * 2e-6 * 500000/24
    __shared__ float2 lut[LUT_N];

    const int t = threadIdx.x;
    {
        const float2* lg = (const float2*)(ws + WS_LUT);
#pragma unroll
        for (int i = 0; i < LUT_N / 256; ++i) lut[t + 256 * i] = lg[t + 256 * i];
    }
    __syncthreads();

    const int lane = t & 63;
    const int wv   = t >> 6;
    const int pix  = (int)blockIdx.x * 4 + wv;   // (n,ho,wo); wo-chunks of 4
    const int n  = pix >> 10;
    const int ho = (pix >> 5) & 31;
    const int wo = pix & 31;

    // lanes 0..8 = taps k; others clamp to tap 8 with zero mask
    const int k9 = lane < 9 ? lane : 8;
    const int di = k9 / 3, dj = k9 % 3;
    const int h = ho + di - 1, w = wo + dj - 1;
    const bool valid = (lane < 9) && (h >= 0) && (h < HH) && (w >= 0) && (w < WW);
    const int hc = min(max(h, 0), HH - 1), wc = min(max(w, 0), WW - 1);
    const float msc = valid ? SZ16 : 0.0f;       // padded tap -> xs = 0 (skipped; ~0 true g)

    const float* xptr = x + n * (CIN * HH * WW) + hc * WW + wc;
    const float* tptr = ws + WS_TAU + k9;

    float accS = 0.f, accB = 0.f;

    float xv = xptr[0];          // prefetch c=0
    float tv = tptr[0];

    for (int c = 0; c < CIN; ++c) {
        // prefetch c+1 (clamped on last iter to stay in-bounds)
        const float* xpn = (c < CIN - 1) ? xptr + HH * WW : xptr;
        const float* tpn = (c < CIN - 1) ? tptr + 9 : tptr;
        float xvn = xpn[0];
        float tvn = tpn[0];
        xptr = xpn; tptr = tpn;

        float xs = xv * msc;                       // scaled tap value (x * 16*SZ)
        unsigned m = (unsigned)__ballot(xs >= tv) & 0x1FFu;
        const int ckb = c * 9;
        while (m) {
            int k = __builtin_ctz(m);
            m &= m - 1;
            int ck = ckb + k;
            float Wv = ws[(ck << 6) + lane];       // coalesced W_T row (L1/L2)
            int xbits = __builtin_amdgcn_readlane(__builtin_bit_cast(int, xs), k);
            float sx = __builtin_bit_cast(float, xbits);   // uniform x*SZ16
            float tt = sx + Wv;                    // LUT coordinate
            float tc = __builtin_amdgcn_fmed3f(tt, 0.0f, 1023.0f);
            unsigned idx = (unsigned)tc;
            float2 sb = lut[idx];
            accS = fmaf(sb.x, tt, accS);           // unclamped t: exact tails
            accB += sb.y;
        }
        xv = xvn; tv = tvn;
    }

    out[((n * 64 + lane) * HH + ho) * WW + wo] = (accS + accB) * OS;
}

extern "C" void kernel_launch(void* const* d_in, const int* in_sizes, int n_in,
                              void* d_out, int out_size, void* d_ws, size_t ws_size,
                              hipStream_t stream) {
    const float* x     = (const float*)d_in[0];   // (4,64,32,32) fp32
    const float* theta = (const float*)d_in[1];   // (64,64,3,3) fp32
    float* out = (float*)d_out;                   // (4,64,32,32) fp32
    float* ws  = (float*)d_ws;

    prep_kernel<<<NW / 256 + 4, 256, 0, stream>>>(theta, ws);

    ekv_kernel<<<1024, 256, 0, stream>>>(x, ws, out);  // 4096 waves = 1/pixel
}

// Round 7
// 81.259 us; speedup vs baseline: 1.3000x; 1.3000x over previous
//
#include <hip/hip_runtime.h>
#include <math.h>

#define HH 32
#define WW 32
#define CIN 64
#define NO 64
#define NCK 576                 // CIN*9
#define LUT_N 1024

// ws float-offsets
#define WS_W   0                // W'[ck][o] = 512/SZ16 - theta[o][ck]   (36864)
#define WS_TAU 36864            // tau[ck] = min_o theta - 8/SZ, +64 pad(1e30)
#define WS_LUT 37504            // float2[1024]: (S*SZ16, B), g = S*SZ16*v + B
#define WS_X   39552            // x copy (262144) + 8192 zero slack
#define X_ELEMS 262144
#define X_SLACK 8192

__global__ __launch_bounds__(256) void prep_kernel(const float* __restrict__ theta,
                                                   const float* __restrict__ x,
                                                   float* __restrict__ ws) {
    const int b = blockIdx.x, t = threadIdx.x;
    const double SZd = 19.235933878519512;       // log2(e)/0.075
    if (b < 144) {                               // W' transform (transposed)
        int i = b * 256 + t;                     // i = ck*64 + o
        int o = i & 63, ck = i >> 6;
        ws[WS_W + i] = (float)(512.0 / (16.0 * SZd)) - theta[o * NCK + ck];
    } else if (b < 147) {                        // tau + pad
        int idx = (b - 144) * 256 + t;
        if (idx < NCK) {
            float mn = 1e30f;
            for (int o = 0; o < NO; ++o) mn = fminf(mn, theta[o * NCK + idx]);
            ws[WS_TAU + idx] = mn - 0.41588896f; // 8/SZ margin (z >= -8 kept)
        } else if (idx < NCK + 64) {
            ws[WS_TAU + idx] = 1e30f;            // never active
        }
    } else if (b < 148) {                        // LUT (double precision build)
        const double D2 = 9.6179661929342026;    // 0.5/(0.075*ln2)
        float2* lut = (float2*)(ws + WS_LUT);
        for (int j = t; j < LUT_N; j += 256) {
            double z0 = -32.0 + j * 0.0625, z1 = z0 + 0.0625;
            double f0 = log2(1.0 + exp2(z0)), f1 = log2(1.0 + exp2(z1));
            double r0 = log2(1.0 + exp2(z0 - D2)), r1 = log2(1.0 + exp2(z1 - D2));
            double g0 = f0 * f0 - r0 * r0, g1 = f1 * f1 - r1 * r1;
            double S = g1 - g0;                  // slope per t-index unit
            double B = g0 - S * (double)j;
            lut[j] = make_float2((float)(S * 16.0 * SZd), (float)B);
        }
    } else {                                     // x copy + zero slack
        int i = (b - 148) * 256 + t;
        ws[WS_X + i] = (i < X_ELEMS) ? x[i] : 0.0f;
    }
}

// lane = output channel o; block = 128 thr = 2 waves = one pixel, c-split 32+32.
// Lanes 0..62 test 7 channels x 9 taps at once (lane l: c_off=l/9, k=l%9);
// ballot -> scalar 63-bit mask; uniform ctz loop over actives only, with the
// coalesced W' row load software-pipelined one active-tap ahead.
__global__ __launch_bounds__(128) void ekv_kernel(
        const float* __restrict__ ws, float* __restrict__ out) {
    constexpr float SZ16 = 307.77494205631218f;  // 16*log2(e)/0.075
    constexpr float OS   = 0.020018875579925058f;

    __shared__ float2 lut[LUT_N];
    __shared__ float  part[64];

    const int t = threadIdx.x;
    {
        const float2* lg = (const float2*)(ws + WS_LUT);
#pragma unroll
        for (int i = 0; i < LUT_N / 128; ++i) lut[t + 128 * i] = lg[t + 128 * i];
    }
    __syncthreads();

    const int lane = t & 63;
    const int wv   = __builtin_amdgcn_readfirstlane(t >> 6);   // scalar wave id
    const int pix  = (int)blockIdx.x;
    const int n  = pix >> 10;
    const int ho = (pix >> 5) & 31;
    const int wo = pix & 31;
    const int c0 = wv * 32;                      // channel half

    // per-lane static decode: l -> (c_off, tap k) ; lane 63 masked out
    int l = lane;
    int c_off = l / 9; if (c_off > 6) c_off = 6;
    int k = l - 9 * c_off; if (k > 8) k = 8;
    int di = k / 3, dj = k - 3 * (k / 3);
    int h = ho + di - 1, w_ = wo + dj - 1;
    bool sval = (h >= 0) && (h < HH) && (w_ >= 0) && (w_ < WW);
    int hc = min(max(h, 0), HH - 1), wc = min(max(w_, 0), WW - 1);
    float msc = ((l < 63) && sval) ? 1.0f : 0.0f;    // pad tap -> xs = 0 (exact)
    int lxoff = c_off * 1024 + hc * WW + wc;

    const float* xw = ws + WS_X + (size_t)(n * CIN + c0) * 1024;
    const float* tw = ws + WS_TAU + c0 * 9;
    const float* wsW = ws + WS_W;

    float accS = 0.f, accB = 0.f;

    float xv = xw[lxoff];        // prefetch chunk 0
    float tv = tw[l];

    for (int cb = 0; cb < 32; cb += 7) {
        int cc = 32 - cb; if (cc > 7) cc = 7;
        // prefetch next chunk's gathers before processing this one
        const float* xw2 = xw + 7 * 1024;
        const float* tw2 = tw + 7 * 9;
        float xvn = xv, tvn = tv;
        if (cb + 7 < 32) { xvn = xw2[lxoff]; tvn = tw2[l]; }

        float xs = xv * msc;
        unsigned long long act = __ballot(xs >= tv);
        act &= (1ull << (cc * 9)) - 1ull;        // kill out-of-chunk lanes

        if (act) {
            const int cb9 = (c0 + cb) * 9;       // ck = cb9 + l  (l = c_off*9+k)
            int il = (int)__builtin_ctzll(act); act &= act - 1;
            float Wv = wsW[((size_t)(cb9 + il) << 6) + lane];

            while (act) {
                int il2 = (int)__builtin_ctzll(act); act &= act - 1;
                float Wv2 = wsW[((size_t)(cb9 + il2) << 6) + lane];  // pipelined
                // body(il, Wv)
                int xb = __builtin_amdgcn_readlane(__builtin_bit_cast(int, xs), il);
                float sx = __builtin_bit_cast(float, xb);
                float v  = Wv + sx;                      // x + W'  (t = SZ16*v)
                float tf = v * SZ16;
                float tc = __builtin_amdgcn_fmed3f(tf, 0.0f, 1023.0f);
                unsigned idx = (unsigned)tc;
                float2 sb = lut[idx];
                accS = fmaf(sb.x, v, accS);              // unclamped v: exact tails
                accB += sb.y;
                il = il2; Wv = Wv2;
            }
            // last active tap
            int xb = __builtin_amdgcn_readlane(__builtin_bit_cast(int, xs), il);
            float sx = __builtin_bit_cast(float, xb);
            float v  = Wv + sx;
            float tf = v * SZ16;
            float tc = __builtin_amdgcn_fmed3f(tf, 0.0f, 1023.0f);
            unsigned idx = (unsigned)tc;
            float2 sb = lut[idx];
            accS = fmaf(sb.x, v, accS);
            accB += sb.y;
        }
        xw = xw2; tw = tw2; xv = xvn; tv = tvn;
    }

    float p = accS + accB;
    if (wv == 1) part[lane] = p;
    __syncthreads();
    if (wv == 0)
        out[((n * NO + lane) * HH + ho) * WW + wo] = (p + part[lane]) * OS;
}

extern "C" void kernel_launch(void* const* d_in, const int* in_sizes, int n_in,
                              void* d_out, int out_size, void* d_ws, size_t ws_size,
                              hipStream_t stream) {
    const float* x     = (const float*)d_in[0];   // (4,64,32,32) fp32
    const float* theta = (const float*)d_in[1];   // (64,64,3,3) fp32
    float* out = (float*)d_out;                   // (4,64,32,32) fp32
    float* ws  = (float*)d_ws;

    int xblocks = (X_ELEMS + X_SLACK) / 256;      // 1056
    prep_kernel<<<148 + xblocks, 256, 0, stream>>>(theta, x, ws);

    ekv_kernel<<<4096, 128, 0, stream>>>(ws, out); // 2 waves/pixel (c-split)
}

// Round 9
// 80.166 us; speedup vs baseline: 1.3177x; 1.0136x over previous
//
#include <hip/hip_runtime.h>
#include <math.h>

#define HH 32
#define WW 32
#define CIN 64
#define NO 64
#define NCK 576                 // CIN*9
#define LUT_N 1024
#define X_ELEMS 262144

// ws float-offsets
#define WS_W   0                // W'[ck][o] = 512/SZ16 - theta[o][ck]   (36864)
#define WS_TAU 36864            // tau[ck] = min_o theta - 8/SZ, +64 pad(1e30)
#define WS_LUT 37504            // float2[1024]: (S*SZ16, B); g = S*SZ16*v + B

__global__ __launch_bounds__(256) void prep_kernel(const float* __restrict__ theta,
                                                   float* __restrict__ ws) {
    const int b = blockIdx.x, t = threadIdx.x;
    const double SZd = 19.235933878519512;       // log2(e)/0.075
    if (b < 144) {                               // W' transform (transposed)
        int i = b * 256 + t;                     // i = ck*64 + o
        int o = i & 63, ck = i >> 6;
        ws[WS_W + i] = (float)(512.0 / (16.0 * SZd)) - theta[o * NCK + ck];
    } else if (b < 147) {                        // tau + pad
        int idx = (b - 144) * 256 + t;
        if (idx < NCK) {
            float mn = 1e30f;
            for (int o = 0; o < NO; ++o) mn = fminf(mn, theta[o * NCK + idx]);
            ws[WS_TAU + idx] = mn - 0.41588896f; // 8/SZ margin (keep z >= -8)
        } else if (idx < NCK + 64) {
            ws[WS_TAU + idx] = 1e30f;            // pad: never active
        }
    } else {                                     // LUT (double precision build)
        const double D2 = 9.6179661929342026;    // 0.5/(0.075*ln2)
        float2* lut = (float2*)(ws + WS_LUT);
        for (int j = t; j < LUT_N; j += 256) {
            double z0 = -32.0 + j * 0.0625, z1 = z0 + 0.0625;
            double f0 = log2(1.0 + exp2(z0)), f1 = log2(1.0 + exp2(z1));
            double r0 = log2(1.0 + exp2(z0 - D2)), r1 = log2(1.0 + exp2(z1 - D2));
            double g0 = f0 * f0 - r0 * r0, g1 = f1 * f1 - r1 * r1;
            double S = g1 - g0;                  // slope per t-index unit
            double B = g0 - S * (double)j;       // entry 0: (~1e-19, ~1e-19)
            lut[j] = make_float2((float)(S * 16.0 * SZd), (float)B);
        }
    }
}

// lane = output channel o; block = 128 thr = 2 waves = one pixel, c-split 32+32.
// Lanes 0..62 test 7 channels x 9 taps at once; ballot -> scalar mask; active
// taps processed 4 per round (depth-4 W-load pipeline). Disabled slots pin
// index 0 (valid W row) and steer tf=-1 -> LUT entry 0 (line ~(0,0)).
__global__ __launch_bounds__(128) void ekv_kernel(
        const float* __restrict__ x, const float* __restrict__ ws,
        float* __restrict__ out) {
    constexpr float SZ16 = 307.77494205631218f;  // 16*log2(e)/0.075
    constexpr float OS   = 0.020018875579925058f;

    __shared__ float2 lut[LUT_N];
    __shared__ float  part[64];

    const int t = threadIdx.x;
    {
        const float2* lg = (const float2*)(ws + WS_LUT);
#pragma unroll
        for (int i = 0; i < LUT_N / 128; ++i) lut[t + 128 * i] = lg[t + 128 * i];
    }
    __syncthreads();

    const int lane = t & 63;
    const int wv   = __builtin_amdgcn_readfirstlane(t >> 6);
    const int pix  = (int)blockIdx.x;
    const int n  = pix >> 10;
    const int ho = (pix >> 5) & 31;
    const int wo = pix & 31;
    const int c0 = wv * 32;

    // lane l -> (c_off = l/9, tap k = l%9); lane 63 decode-clamped + masked
    int l = lane;
    int c_off = l / 9; if (c_off > 6) c_off = 6;
    int k = l - 9 * c_off; if (k > 8) k = 8;
    int di = k / 3, dj = k - 3 * (k / 3);
    int h = ho + di - 1, w_ = wo + dj - 1;
    bool sval = (h >= 0) && (h < HH) && (w_ >= 0) && (w_ < WW);
    int hc = min(max(h, 0), HH - 1), wc = min(max(w_, 0), WW - 1);
    float msc = ((l < 63) && sval) ? 1.0f : 0.0f;    // pad tap -> xs=0 (skipped)

    int gidx = n * (CIN * HH * WW) + (c0 + c_off) * 1024 + hc * WW + wc;
    const float* tw  = ws + WS_TAU + c0 * 9;
    const float* wsW = ws + WS_W;

    float accS = 0.f, accB = 0.f;

    float xv = x[min(gidx, X_ELEMS - 1)];    // chunk 0 gather (OOB lanes masked)
    float tv = tw[l];

    for (int cb = 0; cb < 32; cb += 7) {
        int cc = 32 - cb; if (cc > 7) cc = 7;
        // prefetch next chunk's gathers before processing this one
        int gidx2 = gidx + 7 * 1024;
        const float* tw2 = tw + 63;
        float xvn = xv, tvn = tv;
        if (cb + 7 < 32) { xvn = x[min(gidx2, X_ELEMS - 1)]; tvn = tw2[l]; }

        float xs = xv * msc;
        unsigned long long act = __ballot(xs >= tv);
        act &= (1ull << (cc * 9)) - 1ull;            // kill out-of-chunk lanes

        const int cb9 = (c0 + cb) * 9;               // ck = cb9 + l
        while (act) {
            unsigned long long a = act;
            int i0 = (int)__builtin_ctzll(a);             a &= a - 1;
            bool h1 = a != 0;
            int i1 = a ? (int)__builtin_ctzll(a) : 0;     a &= a - 1;
            bool h2 = a != 0;
            int i2 = a ? (int)__builtin_ctzll(a) : 0;     a &= a - 1;
            bool h3 = a != 0;
            int i3 = a ? (int)__builtin_ctzll(a) : 0;     a &= a - 1;
            act = a;
            // issue all 4 W-row loads (coalesced 256B each) before any body
            float W0 = wsW[((cb9 + i0) << 6) + lane];
            float W1 = wsW[((cb9 + i1) << 6) + lane];
            float W2 = wsW[((cb9 + i2) << 6) + lane];
            float W3 = wsW[((cb9 + i3) << 6) + lane];

#define EKV_BODY(II, WV, EN)                                               \
            {                                                              \
                int xb = __builtin_amdgcn_readlane(                        \
                             __builtin_bit_cast(int, xs), (II));           \
                float sx = __builtin_bit_cast(float, xb);                  \
                float v  = (WV) + sx;                                      \
                float tf = (EN) ? v * SZ16 : -1.0f;                        \
                float tc = __builtin_amdgcn_fmed3f(tf, 0.0f, 1023.0f);     \
                unsigned idx = (unsigned)tc;                               \
                float2 sb = lut[idx];                                      \
                accS = fmaf(sb.x, v, accS);                                \
                accB += sb.y;                                              \
            }
            EKV_BODY(i0, W0, true)
            EKV_BODY(i1, W1, h1)
            EKV_BODY(i2, W2, h2)
            EKV_BODY(i3, W3, h3)
#undef EKV_BODY
        }
        gidx = gidx2; tw = tw2; xv = xvn; tv = tvn;
    }

    float p = accS + accB;
    if (wv == 1) part[lane] = p;
    __syncthreads();
    if (wv == 0)
        out[((n * NO + lane) * HH + ho) * WW + wo] = (p + part[lane]) * OS;
}

extern "C" void kernel_launch(void* const* d_in, const int* in_sizes, int n_in,
                              void* d_out, int out_size, void* d_ws, size_t ws_size,
                              hipStream_t stream) {
    const float* x     = (const float*)d_in[0];   // (4,64,32,32) fp32
    const float* theta = (const float*)d_in[1];   // (64,64,3,3) fp32
    float* out = (float*)d_out;                   // (4,64,32,32) fp32
    float* ws  = (float*)d_ws;

    prep_kernel<<<148, 256, 0, stream>>>(theta, ws);

    ekv_kernel<<<4096, 128, 0, stream>>>(x, ws, out); // 2 waves/pixel (c-split)
}